// Round 1
// baseline (369.967 us; speedup 1.0000x reference)
//
#include <hip/hip_runtime.h>
#include <hip/hip_bf16.h>

typedef __attribute__((ext_vector_type(8))) short s16x8;
typedef __attribute__((ext_vector_type(4))) float f32x4;

#define D_FEAT 512

__device__ __forceinline__ unsigned short f2bf(float f) {
  __hip_bfloat16 h = __float2bfloat16(f);
  return *reinterpret_cast<unsigned short*>(&h);
}

__device__ __forceinline__ void add4(float4& a, const float4 b) {
  a.x += b.x; a.y += b.y; a.z += b.z; a.w += b.w;
}

__device__ __forceinline__ void async16(void* lds, const void* g) {
  __builtin_amdgcn_global_load_lds(
      (const __attribute__((address_space(1))) void*)g,
      (__attribute__((address_space(3))) void*)lds, 16, 0, 0);
}

// ---------------- CSR build ----------------

__global__ void hist_k(const int* __restrict__ dst, int E, int* __restrict__ deg) {
  int i = blockIdx.x * 256 + threadIdx.x;
  if (i < E) atomicAdd(&deg[dst[i]], 1);
}

__global__ void scan_k(const int* __restrict__ deg, int* __restrict__ rowstart, int n) {
  __shared__ int sdata[1024];
  __shared__ int s_carry;
  int tid = threadIdx.x;
  if (tid == 0) s_carry = 0;
  __syncthreads();
  for (int t0 = 0; t0 < n; t0 += 1024) {
    int i = t0 + tid;
    int carry = s_carry;
    int v = (i < n) ? deg[i] : 0;
    sdata[tid] = v;
    __syncthreads();
    for (int off = 1; off < 1024; off <<= 1) {
      int t = (tid >= off) ? sdata[tid - off] : 0;
      __syncthreads();
      sdata[tid] += t;
      __syncthreads();
    }
    if (i < n) rowstart[i] = carry + sdata[tid] - v;
    int total = sdata[1023];
    __syncthreads();
    if (tid == 0) s_carry = carry + total;
    __syncthreads();
  }
  if (tid == 0) rowstart[n] = s_carry;
}

__global__ void fill_k(const int* __restrict__ src, const int* __restrict__ dst, int E,
                       const int* __restrict__ rowstart, int* __restrict__ cursor,
                       int* __restrict__ eperm) {
  int i = blockIdx.x * 256 + threadIdx.x;
  if (i < E) {
    int d = dst[i];
    int pos = atomicAdd(&cursor[d], 1);
    eperm[rowstart[d] + pos] = src[i];
  }
}

// ---------------- aggregation: h = x + sum_{j in N(i)} x_j, stored as bf16 ----------------

__global__ __launch_bounds__(64) void agg_k(const float* __restrict__ x,
                                            const int* __restrict__ rowstart,
                                            const int* __restrict__ eperm,
                                            unsigned short* __restrict__ h) {
  int node = blockIdx.x;
  int lane = threadIdx.x;  // 64 lanes; lane owns dims [4*lane,4*lane+4) and [256+4*lane, ...)
  const float4* xr = (const float4*)(x + (size_t)node * D_FEAT);
  float4 a0 = xr[lane];
  float4 a1 = xr[lane + 64];
  int j = rowstart[node];
  const int end = rowstart[node + 1];
  for (; j + 2 <= end; j += 2) {
    int s0 = eperm[j], s1 = eperm[j + 1];
    const float4* r0 = (const float4*)(x + (size_t)s0 * D_FEAT);
    const float4* r1 = (const float4*)(x + (size_t)s1 * D_FEAT);
    float4 b0 = r0[lane], b1 = r0[lane + 64];
    float4 c0 = r1[lane], c1 = r1[lane + 64];
    add4(a0, b0); add4(a1, b1);
    add4(a0, c0); add4(a1, c1);
  }
  if (j < end) {
    int s0 = eperm[j];
    const float4* r0 = (const float4*)(x + (size_t)s0 * D_FEAT);
    add4(a0, r0[lane]); add4(a1, r0[lane + 64]);
  }
  ushort4 p0 = make_ushort4(f2bf(a0.x), f2bf(a0.y), f2bf(a0.z), f2bf(a0.w));
  ushort4 p1 = make_ushort4(f2bf(a1.x), f2bf(a1.y), f2bf(a1.z), f2bf(a1.w));
  ushort4* hrow = (ushort4*)(h + (size_t)node * D_FEAT);
  hrow[lane] = p0;
  hrow[lane + 64] = p1;
}

// ---------------- weight convert + transpose: Wt[n][k] = bf16(W[k][n]) ----------------

__global__ void wconv_k(const float* __restrict__ W, unsigned short* __restrict__ Wt) {
  int idx = blockIdx.x * 256 + threadIdx.x;  // over 512*512
  int n = idx >> 9, k = idx & 511;
  Wt[idx] = f2bf(W[((size_t)k << 9) + n]);
}

// ---------------- GEMM: C = act(A @ B + bias), A[M,512] bf16 row-major, Bt[512,512] bf16 (B^T) ----------------

template <int RELU, int OUTBF16>
__global__ __launch_bounds__(256) void gemm_k(const unsigned short* __restrict__ A,
                                              const unsigned short* __restrict__ Bt,
                                              const float* __restrict__ bias,
                                              void* __restrict__ Cout, int M) {
  const int K = 512;
  const int NT = 4;  // 512/128 column tiles
  __shared__ unsigned short As[128 * 64];
  __shared__ unsigned short Bs[128 * 64];
  int bid = blockIdx.x;
  int tm = bid / NT, tn = bid % NT;
  int tid = threadIdx.x;
  int wave = tid >> 6, lane = tid & 63;
  int lr = lane & 15, lh = lane >> 4;
  int wm = (wave >> 1) * 64, wn = (wave & 1) * 64;

  f32x4 zero = {0.f, 0.f, 0.f, 0.f};
  f32x4 acc[4][4];
#pragma unroll
  for (int m = 0; m < 4; ++m)
#pragma unroll
    for (int n = 0; n < 4; ++n) acc[m][n] = zero;

  for (int k0 = 0; k0 < K; k0 += 64) {
#pragma unroll
    for (int i = 0; i < 4; ++i) {
      int cb = i * 256 + wave * 64 + lane;  // chunk id, 16B per chunk
      int row = cb >> 3;
      int kc = (cb & 7) * 8;
      int ga = tm * 128 + row;
      if (ga > M - 1) ga = M - 1;  // clamp partial tail tile
      async16(&As[(size_t)(i * 256 + wave * 64) * 8], A + (size_t)ga * K + k0 + kc);
      int gb = tn * 128 + row;  // N=512 exact multiple of 128
      async16(&Bs[(size_t)(i * 256 + wave * 64) * 8], Bt + (size_t)gb * K + k0 + kc);
    }
    __syncthreads();
#pragma unroll
    for (int kk = 0; kk < 64; kk += 32) {
      s16x8 av[4], bv[4];
#pragma unroll
      for (int m = 0; m < 4; ++m)
        av[m] = *(const s16x8*)&As[(wm + m * 16 + lr) * 64 + kk + lh * 8];
#pragma unroll
      for (int n = 0; n < 4; ++n)
        bv[n] = *(const s16x8*)&Bs[(wn + n * 16 + lr) * 64 + kk + lh * 8];
#pragma unroll
      for (int m = 0; m < 4; ++m)
#pragma unroll
        for (int n = 0; n < 4; ++n)
          acc[m][n] = __builtin_amdgcn_mfma_f32_16x16x32_bf16(av[m], bv[n], acc[m][n], 0, 0, 0);
    }
    __syncthreads();
  }

  // epilogue: C/D layout col=lane&15, row=(lane>>4)*4+j  [measured m89]
#pragma unroll
  for (int n = 0; n < 4; ++n) {
    int col = tn * 128 + wn + n * 16 + lr;
    float bval = bias[col];
#pragma unroll
    for (int m = 0; m < 4; ++m) {
#pragma unroll
      for (int j = 0; j < 4; ++j) {
        int row = tm * 128 + wm + m * 16 + lh * 4 + j;
        if (row < M) {
          float v = acc[m][n][j] + bval;
          if (RELU) v = fmaxf(v, 0.f);
          if (OUTBF16)
            ((unsigned short*)Cout)[(size_t)row * 512 + col] = f2bf(v);
          else
            ((float*)Cout)[(size_t)row * 512 + col] = v;
        }
      }
    }
  }
}

// ---------------- launch ----------------

extern "C" void kernel_launch(void* const* d_in, const int* in_sizes, int n_in,
                              void* d_out, int out_size, void* d_ws, size_t ws_size,
                              hipStream_t stream) {
  const float* x = (const float*)d_in[0];
  const int* ei = (const int*)d_in[1];
  const float* W1 = (const float*)d_in[2];
  const float* b1 = (const float*)d_in[3];
  const float* W2 = (const float*)d_in[4];
  const float* b2 = (const float*)d_in[5];
  const int N = in_sizes[0] / D_FEAT;  // 20000
  const int E = in_sizes[1] / 2;       // 640000
  const int* src = ei;
  const int* dst = ei + E;

  char* w = (char*)d_ws;
  auto alloc = [&](size_t bytes) {
    void* p = (void*)w;
    w += (bytes + 255) & ~(size_t)255;
    return p;
  };
  int* eperm = (int*)alloc((size_t)E * 4);
  int* deg = (int*)alloc((size_t)N * 4);
  int* rowstart = (int*)alloc((size_t)(N + 1) * 4);
  int* cursor = (int*)alloc((size_t)N * 4);
  unsigned short* W1t = (unsigned short*)alloc((size_t)512 * 512 * 2);
  unsigned short* W2t = (unsigned short*)alloc((size_t)512 * 512 * 2);
  unsigned short* c1 = (unsigned short*)alloc((size_t)N * 512 * 2);
  // h (bf16) lives in the front of d_out; dead before gemm2 overwrites d_out.
  unsigned short* h = (unsigned short*)d_out;

  hipMemsetAsync(deg, 0, (size_t)N * 4, stream);
  hipMemsetAsync(cursor, 0, (size_t)N * 4, stream);
  hist_k<<<(E + 255) / 256, 256, 0, stream>>>(dst, E, deg);
  scan_k<<<1, 1024, 0, stream>>>(deg, rowstart, N);
  fill_k<<<(E + 255) / 256, 256, 0, stream>>>(src, dst, E, rowstart, cursor, eperm);
  agg_k<<<N, 64, 0, stream>>>(x, rowstart, eperm, h);
  wconv_k<<<1024, 256, 0, stream>>>(W1, W1t);
  wconv_k<<<1024, 256, 0, stream>>>(W2, W2t);
  int mtiles = (N + 127) / 128;
  gemm_k<1, 1><<<mtiles * 4, 256, 0, stream>>>(h, W1t, b1, c1, N);
  gemm_k<0, 0><<<mtiles * 4, 256, 0, stream>>>(c1, W2t, b2, d_out, N);
}

// Round 2
// 271.467 us; speedup vs baseline: 1.3628x; 1.3628x over previous
//
#include <hip/hip_runtime.h>
#include <hip/hip_bf16.h>

typedef __attribute__((ext_vector_type(8))) short s16x8;
typedef __attribute__((ext_vector_type(4))) float f32x4;

#define D_FEAT 512

__device__ __forceinline__ unsigned short f2bf(float f) {
  __hip_bfloat16 h = __float2bfloat16(f);
  return *reinterpret_cast<unsigned short*>(&h);
}

__device__ __forceinline__ float bf2f(short u) {
  union { unsigned int i; float f; } c;
  c.i = ((unsigned int)(unsigned short)u) << 16;
  return c.f;
}

__device__ __forceinline__ void async16(void* lds, const void* g) {
  __builtin_amdgcn_global_load_lds(
      (const __attribute__((address_space(1))) void*)g,
      (__attribute__((address_space(3))) void*)lds, 16, 0, 0);
}

// ---------------- CSR build ----------------

__global__ void hist_k(const int* __restrict__ dst, int E, int* __restrict__ deg) {
  int i = blockIdx.x * 256 + threadIdx.x;
  if (i < E) atomicAdd(&deg[dst[i]], 1);
}

__global__ __launch_bounds__(1024) void scan_k(const int* __restrict__ deg,
                                               int* __restrict__ rowstart, int n) {
  __shared__ int wsum[16];
  __shared__ int carry_s;
  int tid = threadIdx.x;
  int lane = tid & 63, wid = tid >> 6;
  if (tid == 0) carry_s = 0;
  __syncthreads();
  for (int t0 = 0; t0 < n; t0 += 1024) {
    int i = t0 + tid;
    int v = (i < n) ? deg[i] : 0;
    int s = v;  // inclusive wave scan
#pragma unroll
    for (int off = 1; off < 64; off <<= 1) {
      int t = __shfl_up(s, off);
      if (lane >= off) s += t;
    }
    if (lane == 63) wsum[wid] = s;
    __syncthreads();
    if (wid == 0) {
      int ws = (lane < 16) ? wsum[lane] : 0;
#pragma unroll
      for (int off = 1; off < 16; off <<= 1) {
        int t = __shfl_up(ws, off);
        if (lane >= off) ws += t;
      }
      if (lane < 16) wsum[lane] = ws;  // inclusive scan of wave sums
    }
    __syncthreads();
    int carry = carry_s;
    int wbase = (wid > 0) ? wsum[wid - 1] : 0;
    if (i < n) rowstart[i] = carry + wbase + s - v;  // exclusive
    int total = wsum[15];
    __syncthreads();
    if (tid == 0) carry_s = carry + total;
    __syncthreads();
  }
  if (threadIdx.x == 0) rowstart[n] = carry_s;
}

__global__ void fill_k(const int* __restrict__ src, const int* __restrict__ dst, int E,
                       const int* __restrict__ rowstart, int* __restrict__ cursor,
                       int* __restrict__ eperm) {
  int i = blockIdx.x * 256 + threadIdx.x;
  if (i < E) {
    int d = dst[i];
    int pos = atomicAdd(&cursor[d], 1);
    eperm[rowstart[d] + pos] = src[i];
  }
}

// ---------------- x -> bf16 copy ----------------

__global__ __launch_bounds__(256) void xconv_k(const float* __restrict__ x,
                                               unsigned short* __restrict__ xb, int n8) {
  int i = blockIdx.x * 256 + threadIdx.x;
  if (i >= n8) return;
  const float4* p = (const float4*)x + (size_t)i * 2;
  float4 u = p[0], v = p[1];
  s16x8 r;
  r[0] = (short)f2bf(u.x); r[1] = (short)f2bf(u.y);
  r[2] = (short)f2bf(u.z); r[3] = (short)f2bf(u.w);
  r[4] = (short)f2bf(v.x); r[5] = (short)f2bf(v.y);
  r[6] = (short)f2bf(v.z); r[7] = (short)f2bf(v.w);
  ((s16x8*)xb)[i] = r;
}

// ---------------- aggregation: h = x + sum_{j in N(i)} x_j (bf16 gather) ----------------

__global__ __launch_bounds__(64) void agg_k(const unsigned short* __restrict__ xb,
                                            const int* __restrict__ rowstart,
                                            const int* __restrict__ eperm,
                                            unsigned short* __restrict__ h) {
  int node = blockIdx.x;
  int lane = threadIdx.x;  // lane owns dims [8*lane, 8*lane+8): one dwordx4 per row
  const s16x8* xr = (const s16x8*)(xb + (size_t)node * D_FEAT);
  s16x8 own = xr[lane];
  float a[8];
#pragma unroll
  for (int t = 0; t < 8; ++t) a[t] = bf2f(own[t]);
  int j = rowstart[node];
  const int end = rowstart[node + 1];
  for (; j + 4 <= end; j += 4) {
    int s0 = eperm[j], s1 = eperm[j + 1], s2 = eperm[j + 2], s3 = eperm[j + 3];
    s16x8 v0 = ((const s16x8*)(xb + (size_t)s0 * D_FEAT))[lane];
    s16x8 v1 = ((const s16x8*)(xb + (size_t)s1 * D_FEAT))[lane];
    s16x8 v2 = ((const s16x8*)(xb + (size_t)s2 * D_FEAT))[lane];
    s16x8 v3 = ((const s16x8*)(xb + (size_t)s3 * D_FEAT))[lane];
#pragma unroll
    for (int t = 0; t < 8; ++t)
      a[t] += (bf2f(v0[t]) + bf2f(v1[t])) + (bf2f(v2[t]) + bf2f(v3[t]));
  }
  for (; j < end; ++j) {
    int s0 = eperm[j];
    s16x8 v0 = ((const s16x8*)(xb + (size_t)s0 * D_FEAT))[lane];
#pragma unroll
    for (int t = 0; t < 8; ++t) a[t] += bf2f(v0[t]);
  }
  s16x8 r;
#pragma unroll
  for (int t = 0; t < 8; ++t) r[t] = (short)f2bf(a[t]);
  ((s16x8*)(h + (size_t)node * D_FEAT))[lane] = r;
}

// ---------------- weight convert + transpose: Wt[n][k] = bf16(W[k][n]) ----------------

__global__ void wconv_k(const float* __restrict__ W, unsigned short* __restrict__ Wt) {
  int idx = blockIdx.x * 256 + threadIdx.x;  // over 512*512
  int n = idx >> 9, k = idx & 511;
  Wt[idx] = f2bf(W[((size_t)k << 9) + n]);
}

// ---------------- GEMM: C = act(A @ B + bias), A[M,512] bf16 row-major, Bt[512,512] bf16 (B^T) ----------------

template <int RELU, int OUTBF16>
__global__ __launch_bounds__(256) void gemm_k(const unsigned short* __restrict__ A,
                                              const unsigned short* __restrict__ Bt,
                                              const float* __restrict__ bias,
                                              void* __restrict__ Cout, int M) {
  const int K = 512;
  const int NT = 4;  // 512/128 column tiles
  __shared__ unsigned short As[128 * 64];
  __shared__ unsigned short Bs[128 * 64];
  int bid = blockIdx.x;
  int tm = bid / NT, tn = bid % NT;
  int tid = threadIdx.x;
  int wave = tid >> 6, lane = tid & 63;
  int lr = lane & 15, lh = lane >> 4;
  int wm = (wave >> 1) * 64, wn = (wave & 1) * 64;

  f32x4 zero = {0.f, 0.f, 0.f, 0.f};
  f32x4 acc[4][4];
#pragma unroll
  for (int m = 0; m < 4; ++m)
#pragma unroll
    for (int n = 0; n < 4; ++n) acc[m][n] = zero;

  for (int k0 = 0; k0 < K; k0 += 64) {
#pragma unroll
    for (int i = 0; i < 4; ++i) {
      int cb = i * 256 + wave * 64 + lane;  // chunk id, 16B per chunk
      int row = cb >> 3;
      int kc = (cb & 7) * 8;
      int ga = tm * 128 + row;
      if (ga > M - 1) ga = M - 1;  // clamp partial tail tile
      async16(&As[(size_t)(i * 256 + wave * 64) * 8], A + (size_t)ga * K + k0 + kc);
      int gb = tn * 128 + row;  // N=512 exact multiple of 128
      async16(&Bs[(size_t)(i * 256 + wave * 64) * 8], Bt + (size_t)gb * K + k0 + kc);
    }
    __syncthreads();
#pragma unroll
    for (int kk = 0; kk < 64; kk += 32) {
      s16x8 av[4], bv[4];
#pragma unroll
      for (int m = 0; m < 4; ++m)
        av[m] = *(const s16x8*)&As[(wm + m * 16 + lr) * 64 + kk + lh * 8];
#pragma unroll
      for (int n = 0; n < 4; ++n)
        bv[n] = *(const s16x8*)&Bs[(wn + n * 16 + lr) * 64 + kk + lh * 8];
#pragma unroll
      for (int m = 0; m < 4; ++m)
#pragma unroll
        for (int n = 0; n < 4; ++n)
          acc[m][n] = __builtin_amdgcn_mfma_f32_16x16x32_bf16(av[m], bv[n], acc[m][n], 0, 0, 0);
    }
    __syncthreads();
  }

  // epilogue: C/D layout col=lane&15, row=(lane>>4)*4+j  [measured m89]
#pragma unroll
  for (int n = 0; n < 4; ++n) {
    int col = tn * 128 + wn + n * 16 + lr;
    float bval = bias[col];
#pragma unroll
    for (int m = 0; m < 4; ++m) {
#pragma unroll
      for (int j = 0; j < 4; ++j) {
        int row = tm * 128 + wm + m * 16 + lh * 4 + j;
        if (row < M) {
          float v = acc[m][n][j] + bval;
          if (RELU) v = fmaxf(v, 0.f);
          if (OUTBF16)
            ((unsigned short*)Cout)[(size_t)row * 512 + col] = f2bf(v);
          else
            ((float*)Cout)[(size_t)row * 512 + col] = v;
        }
      }
    }
  }
}

// ---------------- launch ----------------

extern "C" void kernel_launch(void* const* d_in, const int* in_sizes, int n_in,
                              void* d_out, int out_size, void* d_ws, size_t ws_size,
                              hipStream_t stream) {
  const float* x = (const float*)d_in[0];
  const int* ei = (const int*)d_in[1];
  const float* W1 = (const float*)d_in[2];
  const float* b1 = (const float*)d_in[3];
  const float* W2 = (const float*)d_in[4];
  const float* b2 = (const float*)d_in[5];
  const int N = in_sizes[0] / D_FEAT;  // 20000
  const int E = in_sizes[1] / 2;       // 640000
  const int* src = ei;
  const int* dst = ei + E;

  char* w = (char*)d_ws;
  auto alloc = [&](size_t bytes) {
    void* p = (void*)w;
    w += (bytes + 255) & ~(size_t)255;
    return p;
  };
  int* eperm = (int*)alloc((size_t)E * 4);
  int* deg = (int*)alloc((size_t)N * 4);
  int* rowstart = (int*)alloc((size_t)(N + 1) * 4);
  int* cursor = (int*)alloc((size_t)N * 4);
  unsigned short* W1t = (unsigned short*)alloc((size_t)512 * 512 * 2);
  unsigned short* W2t = (unsigned short*)alloc((size_t)512 * 512 * 2);
  unsigned short* c1 = (unsigned short*)alloc((size_t)N * 512 * 2);
  // h (bf16) = lower half of d_out; xb (bf16 copy of x) = upper half.
  // Both are dead before gemm2 overwrites d_out with the fp32 result.
  unsigned short* h = (unsigned short*)d_out;
  unsigned short* xb = (unsigned short*)d_out + (size_t)N * D_FEAT;

  hipMemsetAsync(deg, 0, (size_t)N * 4, stream);
  hipMemsetAsync(cursor, 0, (size_t)N * 4, stream);
  hist_k<<<(E + 255) / 256, 256, 0, stream>>>(dst, E, deg);
  scan_k<<<1, 1024, 0, stream>>>(deg, rowstart, N);
  fill_k<<<(E + 255) / 256, 256, 0, stream>>>(src, dst, E, rowstart, cursor, eperm);
  xconv_k<<<(N * D_FEAT / 8 + 255) / 256, 256, 0, stream>>>(x, xb, N * D_FEAT / 8);
  agg_k<<<N, 64, 0, stream>>>(xb, rowstart, eperm, h);
  wconv_k<<<1024, 256, 0, stream>>>(W1, W1t);
  wconv_k<<<1024, 256, 0, stream>>>(W2, W2t);
  int mtiles = (N + 127) / 128;
  gemm_k<1, 1><<<mtiles * 4, 256, 0, stream>>>(h, W1t, b1, c1, N);
  gemm_k<0, 0><<<mtiles * 4, 256, 0, stream>>>(c1, W2t, b2, d_out, N);
}

// Round 3
// 249.044 us; speedup vs baseline: 1.4855x; 1.0900x over previous
//
#include <hip/hip_runtime.h>
#include <hip/hip_bf16.h>

typedef __attribute__((ext_vector_type(8))) short s16x8;
typedef __attribute__((ext_vector_type(4))) float f32x4;

#define D_FEAT 512

__device__ __forceinline__ unsigned short f2bf(float f) {
  __hip_bfloat16 h = __float2bfloat16(f);
  return *reinterpret_cast<unsigned short*>(&h);
}

__device__ __forceinline__ float bf2f(short u) {
  union { unsigned int i; float f; } c;
  c.i = ((unsigned int)(unsigned short)u) << 16;
  return c.f;
}

__device__ __forceinline__ void async16(void* lds, const void* g) {
  __builtin_amdgcn_global_load_lds(
      (const __attribute__((address_space(1))) void*)g,
      (__attribute__((address_space(3))) void*)lds, 16, 0, 0);
}

// ---------------- fused: histogram (deg) + x->bf16 convert ----------------

__global__ __launch_bounds__(256) void hx_k(const int* __restrict__ dst, int E,
                                            int* __restrict__ deg,
                                            const float* __restrict__ x,
                                            unsigned short* __restrict__ xb, int n8, int hb) {
  int bid = blockIdx.x;
  if (bid < hb) {
    int i = bid * 256 + threadIdx.x;
    if (i < E) atomicAdd(&deg[dst[i]], 1);
  } else {
    int i = (bid - hb) * 256 + threadIdx.x;
    if (i < n8) {
      const float4* p = (const float4*)x + (size_t)i * 2;
      float4 u = p[0], v = p[1];
      s16x8 r;
      r[0] = (short)f2bf(u.x); r[1] = (short)f2bf(u.y);
      r[2] = (short)f2bf(u.z); r[3] = (short)f2bf(u.w);
      r[4] = (short)f2bf(v.x); r[5] = (short)f2bf(v.y);
      r[6] = (short)f2bf(v.z); r[7] = (short)f2bf(v.w);
      ((s16x8*)xb)[i] = r;
    }
  }
}

// ---------------- exclusive scan of deg -> rowstart ----------------

__global__ __launch_bounds__(1024) void scan_k(const int* __restrict__ deg,
                                               int* __restrict__ rowstart, int n) {
  __shared__ int wsum[16];
  __shared__ int carry_s;
  int tid = threadIdx.x;
  int lane = tid & 63, wid = tid >> 6;
  if (tid == 0) carry_s = 0;
  __syncthreads();
  for (int t0 = 0; t0 < n; t0 += 1024) {
    int i = t0 + tid;
    int v = (i < n) ? deg[i] : 0;
    int s = v;
#pragma unroll
    for (int off = 1; off < 64; off <<= 1) {
      int t = __shfl_up(s, off);
      if (lane >= off) s += t;
    }
    if (lane == 63) wsum[wid] = s;
    __syncthreads();
    if (wid == 0) {
      int ws = (lane < 16) ? wsum[lane] : 0;
#pragma unroll
      for (int off = 1; off < 16; off <<= 1) {
        int t = __shfl_up(ws, off);
        if (lane >= off) ws += t;
      }
      if (lane < 16) wsum[lane] = ws;
    }
    __syncthreads();
    int carry = carry_s;
    int wbase = (wid > 0) ? wsum[wid - 1] : 0;
    if (i < n) rowstart[i] = carry + wbase + s - v;
    int total = wsum[15];
    __syncthreads();
    if (tid == 0) carry_s = carry + total;
    __syncthreads();
  }
  if (threadIdx.x == 0) rowstart[n] = carry_s;
}

__global__ void fill_k(const int* __restrict__ src, const int* __restrict__ dst, int E,
                       const int* __restrict__ rowstart, int* __restrict__ cursor,
                       int* __restrict__ eperm) {
  int i = blockIdx.x * 256 + threadIdx.x;
  if (i < E) {
    int d = dst[i];
    int pos = atomicAdd(&cursor[d], 1);
    eperm[rowstart[d] + pos] = src[i];
  }
}

// ---------------- aggregation: h = x + sum_{j in N(i)} x_j (bf16 gather), 1 node/wave ----------------

__global__ __launch_bounds__(256) void agg_k(const unsigned short* __restrict__ xb,
                                             const int* __restrict__ rowstart,
                                             const int* __restrict__ eperm,
                                             unsigned short* __restrict__ h, int Nn) {
  int wave = threadIdx.x >> 6, lane = threadIdx.x & 63;
  int node = blockIdx.x * 4 + wave;
  if (node >= Nn) return;
  s16x8 own = ((const s16x8*)(xb + (size_t)node * D_FEAT))[lane];
  float a[8];
#pragma unroll
  for (int t = 0; t < 8; ++t) a[t] = bf2f(own[t]);
  int j = rowstart[node];
  const int end = rowstart[node + 1];
  for (; j + 4 <= end; j += 4) {
    int s0 = eperm[j], s1 = eperm[j + 1], s2 = eperm[j + 2], s3 = eperm[j + 3];
    s16x8 v0 = ((const s16x8*)(xb + (size_t)s0 * D_FEAT))[lane];
    s16x8 v1 = ((const s16x8*)(xb + (size_t)s1 * D_FEAT))[lane];
    s16x8 v2 = ((const s16x8*)(xb + (size_t)s2 * D_FEAT))[lane];
    s16x8 v3 = ((const s16x8*)(xb + (size_t)s3 * D_FEAT))[lane];
#pragma unroll
    for (int t = 0; t < 8; ++t)
      a[t] += (bf2f(v0[t]) + bf2f(v1[t])) + (bf2f(v2[t]) + bf2f(v3[t]));
  }
  for (; j < end; ++j) {
    int s0 = eperm[j];
    s16x8 v0 = ((const s16x8*)(xb + (size_t)s0 * D_FEAT))[lane];
#pragma unroll
    for (int t = 0; t < 8; ++t) a[t] += bf2f(v0[t]);
  }
  s16x8 r;
#pragma unroll
  for (int t = 0; t < 8; ++t) r[t] = (short)f2bf(a[t]);
  ((s16x8*)(h + (size_t)node * D_FEAT))[lane] = r;
}

// ---------------- both weights: Wt[n][k] = bf16(W[k][n]) ----------------

__global__ __launch_bounds__(256) void wconv_k(const float* __restrict__ W1,
                                               const float* __restrict__ W2,
                                               unsigned short* __restrict__ W1t,
                                               unsigned short* __restrict__ W2t) {
  int idx = blockIdx.x * 256 + threadIdx.x;  // over 2 * 512*512
  const float* W = W1;
  unsigned short* Wt = W1t;
  if (idx >= 512 * 512) { idx -= 512 * 512; W = W2; Wt = W2t; }
  int n = idx >> 9, k = idx & 511;
  Wt[idx] = f2bf(W[((size_t)k << 9) + n]);
}

// ---------------- GEMM: C = act(A @ B + bias) ----------------
// A[M,512] bf16 row-major, Bt[512,512] bf16 (B^T). 128x128 tile, BK=64,
// depth-1 prefetch w/ raw barrier + vmcnt(0), XOR-swizzled LDS chunks,
// XCD-chunked block mapping (4 N-tiles of an M-panel share an XCD).

template <int RELU, int OUTBF16>
__global__ __launch_bounds__(256) void gemm_k(const unsigned short* __restrict__ A,
                                              const unsigned short* __restrict__ Bt,
                                              const float* __restrict__ bias,
                                              void* __restrict__ Cout, int M) {
  const int K = 512;
  __shared__ unsigned short As[2][128 * 64];
  __shared__ unsigned short Bs[2][128 * 64];
  int mt = (M + 127) >> 7;
  int qx = (mt + 7) >> 3;  // M-panels per XCD
  int b = blockIdx.x;
  int x = b & 7, i = b >> 3;
  int tm = x * qx + (i >> 2);
  int tn = i & 3;
  if (tm >= mt) return;
  int tid = threadIdx.x;
  int wave = tid >> 6, lane = tid & 63;
  int lr = lane & 15, lh = lane >> 4;
  int p7 = lr & 7;  // row&7 for all fragment rows this lane reads
  int wm = (wave >> 1) * 64, wn = (wave & 1) * 64;

  auto stage = [&](int pb, int k0) {
#pragma unroll
    for (int ii = 0; ii < 4; ++ii) {
      int cb = ii * 256 + wave * 64 + lane;  // chunk id: row = cb>>3, slot c = cb&7
      int row = cb >> 3;
      int cg = (cb & 7) ^ (row & 7);  // inverse-swizzled global chunk
      int ga = tm * 128 + row;
      if (ga > M - 1) ga = M - 1;
      async16(&As[pb][(size_t)(ii * 256 + wave * 64) * 8], A + (size_t)ga * K + k0 + cg * 8);
      int gb = tn * 128 + row;
      async16(&Bs[pb][(size_t)(ii * 256 + wave * 64) * 8], Bt + (size_t)gb * K + k0 + cg * 8);
    }
  };

  f32x4 zero = {0.f, 0.f, 0.f, 0.f};
  f32x4 acc[4][4];
#pragma unroll
  for (int m = 0; m < 4; ++m)
#pragma unroll
    for (int n = 0; n < 4; ++n) acc[m][n] = zero;

  stage(0, 0);
  asm volatile("s_waitcnt vmcnt(0)" ::: "memory");
  __builtin_amdgcn_s_barrier();

  for (int t = 0; t < 8; ++t) {
    int pb = t & 1;
    if (t < 7) stage(pb ^ 1, (t + 1) * 64);
#pragma unroll
    for (int kk = 0; kk < 64; kk += 32) {
      s16x8 av[4], bv[4];
#pragma unroll
      for (int m = 0; m < 4; ++m) {
        int c = ((kk >> 3) + lh) ^ p7;
        av[m] = *(const s16x8*)&As[pb][(wm + m * 16 + lr) * 64 + c * 8];
      }
#pragma unroll
      for (int n = 0; n < 4; ++n) {
        int c = ((kk >> 3) + lh) ^ p7;
        bv[n] = *(const s16x8*)&Bs[pb][(wn + n * 16 + lr) * 64 + c * 8];
      }
#pragma unroll
      for (int m = 0; m < 4; ++m)
#pragma unroll
        for (int n = 0; n < 4; ++n)
          acc[m][n] = __builtin_amdgcn_mfma_f32_16x16x32_bf16(av[m], bv[n], acc[m][n], 0, 0, 0);
    }
    asm volatile("s_waitcnt vmcnt(0)" ::: "memory");
    __builtin_amdgcn_s_barrier();
  }

  // epilogue: C/D layout col=lane&15, row=(lane>>4)*4+j  [measured m89]
#pragma unroll
  for (int n = 0; n < 4; ++n) {
    int col = tn * 128 + wn + n * 16 + lr;
    float bval = bias[col];
#pragma unroll
    for (int m = 0; m < 4; ++m) {
#pragma unroll
      for (int j = 0; j < 4; ++j) {
        int row = tm * 128 + wm + m * 16 + lh * 4 + j;
        if (row < M) {
          float v = acc[m][n][j] + bval;
          if (RELU) v = fmaxf(v, 0.f);
          if (OUTBF16)
            ((unsigned short*)Cout)[(size_t)row * 512 + col] = f2bf(v);
          else
            ((float*)Cout)[(size_t)row * 512 + col] = v;
        }
      }
    }
  }
}

// ---------------- launch ----------------

extern "C" void kernel_launch(void* const* d_in, const int* in_sizes, int n_in,
                              void* d_out, int out_size, void* d_ws, size_t ws_size,
                              hipStream_t stream) {
  const float* x = (const float*)d_in[0];
  const int* ei = (const int*)d_in[1];
  const float* W1 = (const float*)d_in[2];
  const float* b1 = (const float*)d_in[3];
  const float* W2 = (const float*)d_in[4];
  const float* b2 = (const float*)d_in[5];
  const int N = in_sizes[0] / D_FEAT;  // 20000
  const int E = in_sizes[1] / 2;       // 640000
  const int* src = ei;
  const int* dst = ei + E;

  char* w = (char*)d_ws;
  auto alloc = [&](size_t bytes) {
    void* p = (void*)w;
    w += (bytes + 255) & ~(size_t)255;
    return p;
  };
  int* eperm = (int*)alloc((size_t)E * 4);
  int* deg = (int*)alloc((size_t)N * 4);
  int* cursor = (int*)alloc((size_t)N * 4);  // adjacent to deg: one memset
  int* rowstart = (int*)alloc((size_t)(N + 1) * 4);
  unsigned short* W1t = (unsigned short*)alloc((size_t)512 * 512 * 2);
  unsigned short* W2t = (unsigned short*)alloc((size_t)512 * 512 * 2);
  unsigned short* c1 = (unsigned short*)alloc((size_t)N * 512 * 2);
  // h (bf16) = lower half of d_out; xb (bf16 copy of x) = upper half.
  // Both dead before gemm2 overwrites d_out with the fp32 result.
  unsigned short* h = (unsigned short*)d_out;
  unsigned short* xb = (unsigned short*)d_out + (size_t)N * D_FEAT;

  size_t zbytes = (size_t)((char*)cursor - (char*)deg) + (size_t)N * 4;
  hipMemsetAsync(deg, 0, zbytes, stream);
  int hb = (E + 255) / 256;                  // 2500
  int n8 = N * D_FEAT / 8;                   // 1.28M
  int xbk = (n8 + 255) / 256;                // 5000
  hx_k<<<hb + xbk, 256, 0, stream>>>(dst, E, deg, x, xb, n8, hb);
  scan_k<<<1, 1024, 0, stream>>>(deg, rowstart, N);
  fill_k<<<hb, 256, 0, stream>>>(src, dst, E, rowstart, cursor, eperm);
  wconv_k<<<2048, 256, 0, stream>>>(W1, W2, W1t, W2t);
  agg_k<<<(N + 3) / 4, 256, 0, stream>>>(xb, rowstart, eperm, h, N);
  int mt = (N + 127) / 128, qx = (mt + 7) / 8;
  int grid = 8 * qx * 4;
  gemm_k<1, 1><<<grid, 256, 0, stream>>>(h, W1t, b1, c1, N);
  gemm_k<0, 0><<<grid, 256, 0, stream>>>(c1, W2t, b2, d_out, N);
}